// Round 6
// baseline (169.356 us; speedup 1.0000x reference)
//
#include <hip/hip_runtime.h>

// ---------------- types ----------------
typedef __bf16 bf16_8 __attribute__((ext_vector_type(8)));
typedef __bf16 bf16_4 __attribute__((ext_vector_type(4)));
typedef __bf16 bf16_2 __attribute__((ext_vector_type(2)));
typedef float  f32_4  __attribute__((ext_vector_type(4)));
typedef float  f32_16 __attribute__((ext_vector_type(16)));

typedef __attribute__((address_space(1))) const void* as1_cvp;
typedef __attribute__((address_space(3))) void*       as3_vp;

__device__ __forceinline__ void load16_to_lds(const void* g, void* l) {
    __builtin_amdgcn_global_load_lds((as1_cvp)g, (as3_vp)l, 16, 0, 0);
}

// hardware 2^x (v_exp_f32); scale log2(e) is folded into Q at load time
__device__ __forceinline__ float fast_exp2(float x) {
#if __has_builtin(__builtin_amdgcn_exp2f)
    return __builtin_amdgcn_exp2f(x);
#else
    return exp2f(x);
#endif
}

// pack two f32 -> one dword of 2 bf16 (compiler emits cvt+pack)
__device__ __forceinline__ unsigned pk2(float lo, float hi) {
    union { bf16_2 h; unsigned u; } t;
    t.h = bf16_2{(__bf16)lo, (__bf16)hi};
    return t.u;
}

// v_permlane32_swap_b32: a <- [a.lo | b.lo], b <- [a.hi | b.hi]
__device__ __forceinline__ void pswap(unsigned &a, unsigned &b) {
    asm("v_permlane32_swap_b32 %0, %1" : "+v"(a), "+v"(b));
}

// ---------------- fused fp32 -> bf16 convert (x | Wqkv | Wproj) ----------------
__global__ __launch_bounds__(256) void cvt_all(
    const float* __restrict__ a, const float* __restrict__ b,
    const float* __restrict__ c, __bf16* __restrict__ out,
    int na4, int nb4, int nc4)
{
    int i = blockIdx.x * 256 + threadIdx.x;
    if (i >= na4 + nb4 + nc4) return;
    float4 f;
    if (i < na4)            f = ((const float4*)a)[i];
    else if (i < na4 + nb4) f = ((const float4*)b)[i - na4];
    else                    f = ((const float4*)c)[i - na4 - nb4];
    bf16_4 v = { (__bf16)f.x, (__bf16)f.y, (__bf16)f.z, (__bf16)f.w };
    ((bf16_4*)out)[i] = v;
}

// ---------------- bf16 GEMM: C[M,N] = A[M,K] * B[N,K]^T + bias ----------------
// QKV==1: N=3072 logical; cols <2048 (Q|K) stored to Cb with row stride ldc=2048;
// cols >=2048 (V) stored TRANSPOSED to Vtb as [b][h*64+d][t].
// v12: V epilogue goes through an LDS transpose ([128 vcol][130] bf16,
// stride 65 words -> conflict-free) so global stores are coalesced bf16_8
// runs along t, instead of 8B scatter at 4KB lane stride.
#define BM 128

template<int OUT_BF16, int BN_, int QKV>
__global__ __launch_bounds__(256) void gemm_bt(
    const __bf16* __restrict__ A,   // [M,K]
    const __bf16* __restrict__ B,   // [N,K]
    const float*  __restrict__ bias,// [N] or nullptr
    __bf16* __restrict__ Cb, float* __restrict__ Cf,
    __bf16* __restrict__ Vtb,
    int M, int N, int K, int ldc)
{
    constexpr int NT   = BN_ / 32;
    constexpr int CSTR = BN_ + (OUT_BF16 ? 8 : 4);
    __shared__ __align__(16) char smem[35840];
    __bf16* As = (__bf16*)smem;          // [128][64]
    __bf16* Bs = As + 128 * 64;          // [BN_][64]

    const int tid  = threadIdx.x;
    const int wave = tid >> 6;
    const int lane = tid & 63;
    const int wm = wave >> 1, wn = wave & 1;
    const int quad = lane >> 4, l16 = lane & 15;
    const int bm = blockIdx.y * BM, bn = blockIdx.x * BN_;

    const int r0 = tid >> 3;
    const int ch = tid & 7;
    const int cs = (ch ^ (r0 & 7)) * 8;

    f32_4 acc[4][NT];
    #pragma unroll
    for (int i = 0; i < 4; ++i)
        #pragma unroll
        for (int j = 0; j < NT; ++j)
            acc[i][j] = f32_4{0.f, 0.f, 0.f, 0.f};

    for (int k0 = 0; k0 < K; k0 += 64) {
        __syncthreads();
        #pragma unroll
        for (int p = 0; p < 4; ++p) {
            int row = p * 32 + r0;
            load16_to_lds(A + (size_t)(bm + row) * K + k0 + cs,
                          &As[(p * 32 + wave * 8) * 64]);
        }
        #pragma unroll
        for (int p = 0; p < BN_ / 32; ++p) {
            int row = p * 32 + r0;
            load16_to_lds(B + (size_t)(bn + row) * K + k0 + cs,
                          &Bs[(p * 32 + wave * 8) * 64]);
        }
        __syncthreads();

        #pragma unroll
        for (int h = 0; h < 2; ++h) {
            const int sl = ((quad + h * 4) ^ (l16 & 7)) * 8;
            bf16_8 af[4], bfr[NT];
            #pragma unroll
            for (int mt = 0; mt < 4; ++mt)
                af[mt] = *(const bf16_8*)&As[(wm * 64 + mt * 16 + l16) * 64 + sl];
            #pragma unroll
            for (int nt = 0; nt < NT; ++nt)
                bfr[nt] = *(const bf16_8*)&Bs[(wn * (BN_/2) + nt * 16 + l16) * 64 + sl];
            #pragma unroll
            for (int mt = 0; mt < 4; ++mt)
                #pragma unroll
                for (int nt = 0; nt < NT; ++nt)
                    acc[mt][nt] = __builtin_amdgcn_mfma_f32_16x16x32_bf16(
                        af[mt], bfr[nt], acc[mt][nt], 0, 0, 0);
        }
    }

    __syncthreads();   // K-loop LDS reads complete before epilogue reuse

    if (QKV && bn >= 2048) {
        // ---- V tile: transpose via LDS, then coalesced stores along t ----
        // acc row_local (t) = wm*64+mt*16+quad*4+r, col_local (vrow) = wn*64+nt*16+l16
        constexpr int VSTR = 130;   // 65 words: conflict-free column writes
        __bf16* Cs = (__bf16*)smem; // [128 vcol][VSTR]
        const int b_ = bm >> 11;
        const int t_base = bm & 2047;
        #pragma unroll
        for (int nt = 0; nt < NT; ++nt) {
            int colL = wn * (BN_/2) + nt * 16 + l16;
            float bv = bias ? bias[2048 + (bn - 2048) + colL] : 0.f;
            #pragma unroll
            for (int mt = 0; mt < 4; ++mt) {
                bf16_4 ov;
                #pragma unroll
                for (int r = 0; r < 4; ++r)
                    ov[r] = (__bf16)(acc[mt][nt][r] + bv);
                *(bf16_4*)&Cs[colL * VSTR + wm * 64 + mt * 16 + quad * 4] = ov;
            }
        }
        __syncthreads();
        const int rr = tid >> 4, cc = (tid & 15) * 8;
        #pragma unroll
        for (int p = 0; p < 8; ++p) {
            int vr = p * 16 + rr;   // vrow-offset within this 128-col block
            bf16_8 v = *(const bf16_8*)&Cs[vr * VSTR + cc];
            *(bf16_8*)(Vtb + ((size_t)b_ * 1024 + (bn - 2048) + vr) * 2048
                       + t_base + cc) = v;
        }
        return;
    }

    if (OUT_BF16) {
        __bf16* Cs = (__bf16*)smem;
        #pragma unroll
        for (int mt = 0; mt < 4; ++mt)
            #pragma unroll
            for (int nt = 0; nt < NT; ++nt) {
                int col = wn * (BN_/2) + nt * 16 + l16;
                float bv = bias ? bias[bn + col] : 0.f;
                #pragma unroll
                for (int r = 0; r < 4; ++r)
                    Cs[(wm * 64 + mt * 16 + quad * 4 + r) * CSTR + col] =
                        (__bf16)(acc[mt][nt][r] + bv);
            }
        __syncthreads();
        const int rr = tid >> 4, cc = (tid & 15) * 8;
        #pragma unroll
        for (int p = 0; p < 8; ++p) {
            int row = p * 16 + rr;
            bf16_8 v = *(const bf16_8*)&Cs[row * CSTR + cc];
            *(bf16_8*)(Cb + (size_t)(bm + row) * ldc + bn + cc) = v;
        }
    } else {
        float* Cs = (float*)smem;
        #pragma unroll
        for (int mt = 0; mt < 4; ++mt)
            #pragma unroll
            for (int nt = 0; nt < NT; ++nt) {
                int col = wn * (BN_/2) + nt * 16 + l16;
                float bv = bias ? bias[bn + col] : 0.f;
                #pragma unroll
                for (int r = 0; r < 4; ++r)
                    Cs[(wm * 64 + mt * 16 + quad * 4 + r) * CSTR + col] =
                        acc[mt][nt][r] + bv;
            }
        __syncthreads();
        const int rr = tid >> 4, cc = (tid & 15) * 4;
        #pragma unroll
        for (int p = 0; p < 8; ++p) {
            int row = p * 16 + rr;
            float4 v = *(const float4*)&Cs[row * CSTR + cc];
            *(float4*)(Cf + (size_t)(bm + row) * ldc + bn + cc) = v;
        }
    }
}

// ---------------- causal flash attention v11: 32x32 MFMA + counted vmcnt ----------------
// Triple-buffered K/V staging with counted s_waitcnt vmcnt(4) + raw s_barrier.
// Tile j+2 issued right after the barrier of iter j -> ~2 compute iterations
// for loads to land. Verified R5: total 176 -> 164 us.
__global__ __launch_bounds__(256, 2) void attn_kernel(
    const __bf16* __restrict__ qk, const __bf16* __restrict__ vt,
    __bf16* __restrict__ out)
{
    constexpr int T = 2048;
    __shared__ __align__(16) char pool[49152];
    __bf16* Ks = (__bf16*)pool;             // [3][64 keys][64 d] chunk-swizzled
    __bf16* Vt = (__bf16*)(pool + 24576);   // [3][64 d][64 t]  chunk-swizzled
    float*  Om = (float*)pool;              // alias: [128][68] f32 (34816 B)
    float*  Lm = (float*)(pool + 34816);    // [128]

    const int tid  = threadIdx.x;
    const int wave = tid >> 6;
    const int lane = tid & 63;
    const int wq = wave & 1, wg = wave >> 1;
    const int l32 = lane & 31, hh = lane >> 5;

    const int fid  = blockIdx.x;            // 0..511
    const int xcd  = fid & 7;
    const int hsel = fid >> 8;
    const int w    = (fid >> 3) & 31;
    const int qt   = hsel ? (7 - (w >> 2)) : ((w >> 2) + 8);
    const int bh   = xcd * 4 + (w & 3);
    const int b = bh >> 4, h = bh & 15;
    const int jmax = 2 * qt + 1;

    const size_t rowbase = (size_t)b * T;
    const __bf16* Kbase = qk + 1024 + h * 64;            // row stride 2048
    const __bf16* Vbase = vt + (size_t)bh * 64 * 2048;   // [d][t]

    // staging: 4x load16 per thread per tile (2 K rows-chunks + 2 V)
    const int sr   = tid >> 3;              // 0..31
    const int schf = (tid & 7) ^ (sr & 7);  // (sr+32)&7 == sr&7

    // ---- Q fragments (B-operand), scale*log2(e) folded ----
    constexpr float QSCALE = 0.125f * 1.4426950408889634f;
    bf16_8 aq[2][4];   // [qtile][d-frag]
    #pragma unroll
    for (int qq = 0; qq < 2; ++qq)
        #pragma unroll
        for (int df = 0; df < 4; ++df) {
            const __bf16* qp = qk + (rowbase + qt*128 + wq*64 + qq*32 + l32)*2048
                               + h*64 + df*16 + hh*8;
            bf16_8 v = *(const bf16_8*)qp;
            #pragma unroll
            for (int u = 0; u < 8; ++u) v[u] = (__bf16)((float)v[u] * QSCALE);
            aq[qq][df] = v;
        }

    // ---- prologue: stage tiles 0 and 1 into bufs 0 and 1 ----
    #pragma unroll
    for (int t0 = 0; t0 < 2; ++t0)
        #pragma unroll
        for (int p = 0; p < 2; ++p) {
            load16_to_lds(Kbase + (rowbase + t0*64 + sr + 32*p)*2048 + schf*8,
                          Ks + t0*4096 + p*2048 + wave*512);
            load16_to_lds(Vbase + (size_t)(sr + 32*p)*2048 + t0*64 + schf*8,
                          Vt + t0*4096 + p*2048 + wave*512);
        }

    f32_16 O[2][2];   // [dtile][qtile]
    #pragma unroll
    for (int dt = 0; dt < 2; ++dt)
        #pragma unroll
        for (int qq = 0; qq < 2; ++qq)
            #pragma unroll
            for (int r = 0; r < 16; ++r) O[dt][qq][r] = 0.f;
    float l_i[2] = {0.f, 0.f};

    int cur = 0;       // buf index of tile j
    int sb  = 2;       // buf index of tile j+2 (stage target)
    for (int j = 0; j <= jmax; ++j) {
        // tile j staged? (its 4 loads are the oldest; tile j+1's 4 may fly)
        if (j < jmax) asm volatile("s_waitcnt vmcnt(4)" ::: "memory");
        else          asm volatile("s_waitcnt vmcnt(0)" ::: "memory");
        __builtin_amdgcn_s_barrier();   // all waves: tile j staged, buf[sb] reads done

        const int jn = j + 2;
        if (jn <= jmax) {
            #pragma unroll
            for (int p = 0; p < 2; ++p) {
                load16_to_lds(Kbase + (rowbase + jn*64 + sr + 32*p)*2048 + schf*8,
                              Ks + sb*4096 + p*2048 + wave*512);
                load16_to_lds(Vbase + (size_t)(sr + 32*p)*2048 + jn*64 + schf*8,
                              Vt + sb*4096 + p*2048 + wave*512);
            }
        }

        // ---- S^T[32k x 64q] = K Q^T : A=K-frag, B=Q-frag, d-chained x4 ----
        const int krow = wg*32 + l32;
        const int ksw  = krow & 7;
        f32_16 S[2];
        __builtin_amdgcn_s_setprio(1);
        bf16_8 kf[4];
        #pragma unroll
        for (int df = 0; df < 4; ++df)
            kf[df] = *(const bf16_8*)&Ks[cur*4096 + krow*64 + (((2*df + hh) ^ ksw) << 3)];
        #pragma unroll
        for (int qq = 0; qq < 2; ++qq) {
            f32_16 z;
            #pragma unroll
            for (int r = 0; r < 16; ++r) z[r] = 0.f;
            #pragma unroll
            for (int df = 0; df < 4; ++df)
                z = __builtin_amdgcn_mfma_f32_32x32x16_bf16(kf[df], aq[qq][df], z, 0, 0, 0);
            S[qq] = z;
        }
        __builtin_amdgcn_s_setprio(0);

        // ---- exp2 + causal mask; pack P^T into PV B-frags (VALU only) ----
        const bool diag = (j >= 2*qt);
        unsigned fr[2][8];   // [qtile][khalf*4 + dword]
        #pragma unroll
        for (int qq = 0; qq < 2; ++qq) {
            float pe[16];
            const int qg = qt*128 + wq*64 + qq*32 + l32;
            #pragma unroll
            for (int r = 0; r < 16; ++r) {
                float e = fast_exp2(S[qq][r]);
                if (diag) {
                    int key = j*64 + wg*32 + (r&3) + 8*(r>>2) + 4*hh;
                    if (key > qg) e = 0.f;
                }
                pe[r] = e;
                l_i[qq] += e;
            }
            unsigned A = pk2(pe[0],  pe[1]),  Bv = pk2(pe[2],  pe[3]),
                     C = pk2(pe[4],  pe[5]),  D  = pk2(pe[6],  pe[7]),
                     E = pk2(pe[8],  pe[9]),  F  = pk2(pe[10], pe[11]),
                     G = pk2(pe[12], pe[13]), H  = pk2(pe[14], pe[15]);
            pswap(A, C); pswap(Bv, D); pswap(E, G); pswap(F, H);
            fr[qq][0] = A; fr[qq][1] = Bv; fr[qq][2] = C; fr[qq][3] = D;
            fr[qq][4] = E; fr[qq][5] = F;  fr[qq][6] = G; fr[qq][7] = H;
        }

        // ---- O^T += V^T P^T : A=V-frag (b128), B=P-frag (regs) ----
        __builtin_amdgcn_s_setprio(1);
        #pragma unroll
        for (int kh = 0; kh < 2; ++kh) {
            #pragma unroll
            for (int dt = 0; dt < 2; ++dt) {
                const int d = dt*32 + l32;
                bf16_8 vf = *(const bf16_8*)&Vt[cur*4096 + d*64 +
                                (((wg*4 + kh*2 + hh) ^ (d & 7)) << 3)];
                #pragma unroll
                for (int qq = 0; qq < 2; ++qq) {
                    union { unsigned dw[4]; bf16_8 v; } u;
                    u.dw[0] = fr[qq][kh*4+0]; u.dw[1] = fr[qq][kh*4+1];
                    u.dw[2] = fr[qq][kh*4+2]; u.dw[3] = fr[qq][kh*4+3];
                    O[dt][qq] = __builtin_amdgcn_mfma_f32_32x32x16_bf16(
                        vf, u.v, O[dt][qq], 0, 0, 0);
                }
            }
        }
        __builtin_amdgcn_s_setprio(0);

        cur = (cur == 2) ? 0 : cur + 1;
        sb  = (sb  == 2) ? 0 : sb  + 1;
    }

    // ---- l: own 16 rows + partner half via xor-32 ----
    float lw[2];
    #pragma unroll
    for (int qq = 0; qq < 2; ++qq) {
        float v = l_i[qq];
        v += __shfl_xor(v, 32, 64);
        lw[qq] = v;
    }

    // ---- 2-way wg merge via LDS (Om aliases K/V pool) ----
    __syncthreads();   // all Ks/Vt reads done before Om aliases the pool
    if (wg == 1) {
        #pragma unroll
        for (int qq = 0; qq < 2; ++qq) {
            const int qrow = wq*64 + qq*32 + l32;
            #pragma unroll
            for (int dt = 0; dt < 2; ++dt)
                #pragma unroll
                for (int g = 0; g < 4; ++g) {
                    f32_4 t = { O[dt][qq][g*4+0], O[dt][qq][g*4+1],
                                O[dt][qq][g*4+2], O[dt][qq][g*4+3] };
                    *(f32_4*)&Om[qrow*68 + dt*32 + g*8 + hh*4] = t;
                }
            if (hh == 0) Lm[qrow] = lw[qq];
        }
    }
    __syncthreads();
    if (wg == 0) {
        #pragma unroll
        for (int qq = 0; qq < 2; ++qq) {
            const int qrow = wq*64 + qq*32 + l32;
            const float inv = 1.f / (lw[qq] + Lm[qrow]);
            const size_t obase = (rowbase + qt*128 + qrow) * 1024 + h*64;
            #pragma unroll
            for (int dt = 0; dt < 2; ++dt)
                #pragma unroll
                for (int g = 0; g < 4; ++g) {
                    f32_4 o2 = *(const f32_4*)&Om[qrow*68 + dt*32 + g*8 + hh*4];
                    bf16_4 ov;
                    #pragma unroll
                    for (int r = 0; r < 4; ++r)
                        ov[r] = (__bf16)((O[dt][qq][g*4+r] + o2[r]) * inv);
                    *(bf16_4*)(out + obase + dt*32 + g*8 + hh*4) = ov;
                }
        }
    }
}

// ---------------- launch ----------------
extern "C" void kernel_launch(void* const* d_in, const int* in_sizes, int n_in,
                              void* d_out, int out_size, void* d_ws, size_t ws_size,
                              hipStream_t stream)
{
    constexpr int Bc = 2, Tc = 2048, Dc = 1024;
    constexpr int M  = Bc * Tc;
    constexpr int N1 = 3 * Dc;

    const float* x     = (const float*)d_in[0];
    const float* Wqkv  = (const float*)d_in[1];
    const float* bqkv  = (const float*)d_in[2];
    const float* Wproj = (const float*)d_in[3];
    const float* bproj = (const float*)d_in[4];
    float* outp = (float*)d_out;

    __bf16* xb     = (__bf16*)d_ws;                        // 4096*1024
    __bf16* wqkvb  = xb     + (size_t)M * Dc;              // 3072*1024
    __bf16* wprojb = wqkvb  + (size_t)N1 * Dc;             // 1024*1024
    __bf16* qkb    = wprojb + (size_t)Dc * Dc;             // 4096*2048 (Q|K)
    __bf16* vtb    = qkb    + (size_t)M * 2048;            // 2*1024*2048 (V^T)
    __bf16* attnb  = vtb    + (size_t)Bc * 1024 * 2048;    // 4096*1024

    {
        int na4 = M * Dc / 4, nb4 = N1 * Dc / 4, nc4 = Dc * Dc / 4;
        int n4 = na4 + nb4 + nc4;
        cvt_all<<<(n4 + 255) / 256, 256, 0, stream>>>(x, Wqkv, Wproj, xb, na4, nb4, nc4);
    }

    gemm_bt<1, 128, 1><<<dim3(N1 / 128, M / BM), 256, 0, stream>>>(
        xb, wqkvb, bqkv, qkb, nullptr, vtb, M, N1, Dc, 2048);

    attn_kernel<<<dim3(512), 256, 0, stream>>>(qkb, vtb, attnb);

    gemm_bt<0, 64, 0><<<dim3(Dc / 64, M / BM), 256, 0, stream>>>(
        attnb, wprojb, bproj, nullptr, outp, nullptr, M, Dc, Dc, Dc);
}

// Round 7
// 162.838 us; speedup vs baseline: 1.0400x; 1.0400x over previous
//
#include <hip/hip_runtime.h>

// ---------------- types ----------------
typedef __bf16 bf16_8 __attribute__((ext_vector_type(8)));
typedef __bf16 bf16_4 __attribute__((ext_vector_type(4)));
typedef __bf16 bf16_2 __attribute__((ext_vector_type(2)));
typedef float  f32_4  __attribute__((ext_vector_type(4)));
typedef float  f32_16 __attribute__((ext_vector_type(16)));

typedef __attribute__((address_space(1))) const void* as1_cvp;
typedef __attribute__((address_space(3))) void*       as3_vp;

__device__ __forceinline__ void load16_to_lds(const void* g, void* l) {
    __builtin_amdgcn_global_load_lds((as1_cvp)g, (as3_vp)l, 16, 0, 0);
}

// hardware 2^x (v_exp_f32); scale log2(e) is folded into Q at load time
__device__ __forceinline__ float fast_exp2(float x) {
#if __has_builtin(__builtin_amdgcn_exp2f)
    return __builtin_amdgcn_exp2f(x);
#else
    return exp2f(x);
#endif
}

// pack two f32 -> one dword of 2 bf16 (compiler emits cvt+pack)
__device__ __forceinline__ unsigned pk2(float lo, float hi) {
    union { bf16_2 h; unsigned u; } t;
    t.h = bf16_2{(__bf16)lo, (__bf16)hi};
    return t.u;
}

// v_permlane32_swap_b32: a <- [a.lo | b.lo], b <- [a.hi | b.hi]
__device__ __forceinline__ void pswap(unsigned &a, unsigned &b) {
    asm("v_permlane32_swap_b32 %0, %1" : "+v"(a), "+v"(b));
}

// ---------------- fused fp32 -> bf16 convert (x | Wqkv | Wproj) ----------------
__global__ __launch_bounds__(256) void cvt_all(
    const float* __restrict__ a, const float* __restrict__ b,
    const float* __restrict__ c, __bf16* __restrict__ out,
    int na4, int nb4, int nc4)
{
    int i = blockIdx.x * 256 + threadIdx.x;
    if (i >= na4 + nb4 + nc4) return;
    float4 f;
    if (i < na4)            f = ((const float4*)a)[i];
    else if (i < na4 + nb4) f = ((const float4*)b)[i - na4];
    else                    f = ((const float4*)c)[i - na4 - nb4];
    bf16_4 v = { (__bf16)f.x, (__bf16)f.y, (__bf16)f.z, (__bf16)f.w };
    ((bf16_4*)out)[i] = v;
}

// ---------------- bf16 GEMM: C[M,N] = A[M,K] * B[N,K]^T + bias ----------------
// QKV==1: N=3072 logical; cols <2048 (Q|K) stored to Cb with row stride ldc=2048;
// cols >=2048 (V) stored TRANSPOSED to Vtb as [b][h*64+d][t] directly from
// accumulators (R5-verified direct stores; R6's LDS transpose regressed).
// PIPE==1 (proj): triple-buffered staging + counted s_waitcnt vmcnt(6) +
// raw s_barrier (T4) -- proj runs 2 blocks/CU = 2 waves/SIMD, the low-TLP
// regime where the per-iter vmcnt(0) drain is exposed (same mechanism that
// won -12us in attn R5). QKV (3 blocks/CU) keeps the 2-barrier path
// (source pipelining documented-null at >=3 waves/SIMD).
#define BM 128

template<int OUT_BF16, int BN_, int QKV, int PIPE>
__global__ __launch_bounds__(256) void gemm_bt(
    const __bf16* __restrict__ A,   // [M,K]
    const __bf16* __restrict__ B,   // [N,K]
    const float*  __restrict__ bias,// [N] or nullptr
    __bf16* __restrict__ Cb, float* __restrict__ Cf,
    __bf16* __restrict__ Vtb,
    int M, int N, int K, int ldc)
{
    constexpr int NT   = BN_ / 32;
    constexpr int CSTR = BN_ + (OUT_BF16 ? 8 : 4);
    constexpr int BUFB = (128 * 64 + BN_ * 64) * 2;          // bytes per stage buf
    constexpr int SMEMSZ = PIPE ? (3 * BUFB) : 35840;
    __shared__ __align__(16) char smem[SMEMSZ];

    const int tid  = threadIdx.x;
    const int wave = tid >> 6;
    const int lane = tid & 63;
    const int wm = wave >> 1, wn = wave & 1;
    const int quad = lane >> 4, l16 = lane & 15;
    const int bm = blockIdx.y * BM, bn = blockIdx.x * BN_;

    const int r0 = tid >> 3;
    const int ch = tid & 7;
    const int cs = (ch ^ (r0 & 7)) * 8;

    f32_4 acc[4][NT];
    #pragma unroll
    for (int i = 0; i < 4; ++i)
        #pragma unroll
        for (int j = 0; j < NT; ++j)
            acc[i][j] = f32_4{0.f, 0.f, 0.f, 0.f};

    if constexpr (!PIPE) {
        __bf16* As = (__bf16*)smem;          // [128][64]
        __bf16* Bs = As + 128 * 64;          // [BN_][64]
        for (int k0 = 0; k0 < K; k0 += 64) {
            __syncthreads();
            #pragma unroll
            for (int p = 0; p < 4; ++p) {
                int row = p * 32 + r0;
                load16_to_lds(A + (size_t)(bm + row) * K + k0 + cs,
                              &As[(p * 32 + wave * 8) * 64]);
            }
            #pragma unroll
            for (int p = 0; p < BN_ / 32; ++p) {
                int row = p * 32 + r0;
                load16_to_lds(B + (size_t)(bn + row) * K + k0 + cs,
                              &Bs[(p * 32 + wave * 8) * 64]);
            }
            __syncthreads();

            #pragma unroll
            for (int h = 0; h < 2; ++h) {
                const int sl = ((quad + h * 4) ^ (l16 & 7)) * 8;
                bf16_8 af[4], bfr[NT];
                #pragma unroll
                for (int mt = 0; mt < 4; ++mt)
                    af[mt] = *(const bf16_8*)&As[(wm * 64 + mt * 16 + l16) * 64 + sl];
                #pragma unroll
                for (int nt = 0; nt < NT; ++nt)
                    bfr[nt] = *(const bf16_8*)&Bs[(wn * (BN_/2) + nt * 16 + l16) * 64 + sl];
                #pragma unroll
                for (int mt = 0; mt < 4; ++mt)
                    #pragma unroll
                    for (int nt = 0; nt < NT; ++nt)
                        acc[mt][nt] = __builtin_amdgcn_mfma_f32_16x16x32_bf16(
                            af[mt], bfr[nt], acc[mt][nt], 0, 0, 0);
            }
        }
    } else {
        // ---- T4: triple-buffered, counted vmcnt; 6 loads/thread/tile ----
        const int nit = K / 64;
        #pragma unroll
        for (int t = 0; t < 2; ++t) {
            __bf16* AsT = (__bf16*)(smem + t * BUFB);
            __bf16* BsT = AsT + 128 * 64;
            #pragma unroll
            for (int p = 0; p < 4; ++p)
                load16_to_lds(A + (size_t)(bm + p * 32 + r0) * K + t * 64 + cs,
                              &AsT[(p * 32 + wave * 8) * 64]);
            #pragma unroll
            for (int p = 0; p < BN_ / 32; ++p)
                load16_to_lds(B + (size_t)(bn + p * 32 + r0) * K + t * 64 + cs,
                              &BsT[(p * 32 + wave * 8) * 64]);
        }
        int cur = 0, sb = 2;
        for (int j = 0; j < nit; ++j) {
            if (j < nit - 1) asm volatile("s_waitcnt vmcnt(6)" ::: "memory");
            else             asm volatile("s_waitcnt vmcnt(0)" ::: "memory");
            __builtin_amdgcn_s_barrier();   // tile j staged; buf[sb] reads done

            if (j + 2 < nit) {
                const int k0 = (j + 2) * 64;
                __bf16* AsT = (__bf16*)(smem + sb * BUFB);
                __bf16* BsT = AsT + 128 * 64;
                #pragma unroll
                for (int p = 0; p < 4; ++p)
                    load16_to_lds(A + (size_t)(bm + p * 32 + r0) * K + k0 + cs,
                                  &AsT[(p * 32 + wave * 8) * 64]);
                #pragma unroll
                for (int p = 0; p < BN_ / 32; ++p)
                    load16_to_lds(B + (size_t)(bn + p * 32 + r0) * K + k0 + cs,
                                  &BsT[(p * 32 + wave * 8) * 64]);
            }

            __bf16* As = (__bf16*)(smem + cur * BUFB);
            __bf16* Bs = As + 128 * 64;
            #pragma unroll
            for (int h = 0; h < 2; ++h) {
                const int sl = ((quad + h * 4) ^ (l16 & 7)) * 8;
                bf16_8 af[4], bfr[NT];
                #pragma unroll
                for (int mt = 0; mt < 4; ++mt)
                    af[mt] = *(const bf16_8*)&As[(wm * 64 + mt * 16 + l16) * 64 + sl];
                #pragma unroll
                for (int nt = 0; nt < NT; ++nt)
                    bfr[nt] = *(const bf16_8*)&Bs[(wn * (BN_/2) + nt * 16 + l16) * 64 + sl];
                #pragma unroll
                for (int mt = 0; mt < 4; ++mt)
                    #pragma unroll
                    for (int nt = 0; nt < NT; ++nt)
                        acc[mt][nt] = __builtin_amdgcn_mfma_f32_16x16x32_bf16(
                            af[mt], bfr[nt], acc[mt][nt], 0, 0, 0);
            }
            cur = (cur == 2) ? 0 : cur + 1;
            sb  = (sb  == 2) ? 0 : sb  + 1;
        }
    }

    if (QKV && bn >= 2048) {
        // ---- V tile: store transposed directly (V^T[b][h*64+d][t]) ----
        const int b_ = bm >> 11;
        const int t0 = (bm & 2047) + wm * 64;
        #pragma unroll
        for (int nt = 0; nt < NT; ++nt) {
            int vrow = (bn - 2048) + wn * (BN_/2) + nt * 16 + l16;   // h*64+d
            float bv = bias ? bias[2048 + vrow] : 0.f;
            #pragma unroll
            for (int mt = 0; mt < 4; ++mt) {
                bf16_4 ov;
                #pragma unroll
                for (int r = 0; r < 4; ++r)
                    ov[r] = (__bf16)(acc[mt][nt][r] + bv);
                *(bf16_4*)(Vtb + ((size_t)b_ * 1024 + vrow) * 2048
                           + t0 + mt * 16 + quad * 4) = ov;
            }
        }
        return;
    }

    __syncthreads();

    if (OUT_BF16) {
        __bf16* Cs = (__bf16*)smem;
        #pragma unroll
        for (int mt = 0; mt < 4; ++mt)
            #pragma unroll
            for (int nt = 0; nt < NT; ++nt) {
                int col = wn * (BN_/2) + nt * 16 + l16;
                float bv = bias ? bias[bn + col] : 0.f;
                #pragma unroll
                for (int r = 0; r < 4; ++r)
                    Cs[(wm * 64 + mt * 16 + quad * 4 + r) * CSTR + col] =
                        (__bf16)(acc[mt][nt][r] + bv);
            }
        __syncthreads();
        const int rr = tid >> 4, cc = (tid & 15) * 8;
        #pragma unroll
        for (int p = 0; p < 8; ++p) {
            int row = p * 16 + rr;
            bf16_8 v = *(const bf16_8*)&Cs[row * CSTR + cc];
            *(bf16_8*)(Cb + (size_t)(bm + row) * ldc + bn + cc) = v;
        }
    } else {
        float* Cs = (float*)smem;
        #pragma unroll
        for (int mt = 0; mt < 4; ++mt)
            #pragma unroll
            for (int nt = 0; nt < NT; ++nt) {
                int col = wn * (BN_/2) + nt * 16 + l16;
                float bv = bias ? bias[bn + col] : 0.f;
                #pragma unroll
                for (int r = 0; r < 4; ++r)
                    Cs[(wm * 64 + mt * 16 + quad * 4 + r) * CSTR + col] =
                        acc[mt][nt][r] + bv;
            }
        __syncthreads();
        const int rr = tid >> 4, cc = (tid & 15) * 4;
        #pragma unroll
        for (int p = 0; p < 8; ++p) {
            int row = p * 16 + rr;
            float4 v = *(const float4*)&Cs[row * CSTR + cc];
            *(float4*)(Cf + (size_t)(bm + row) * ldc + bn + cc) = v;
        }
    }
}

// ---------------- causal flash attention v11: 32x32 MFMA + counted vmcnt ----------------
// Triple-buffered K/V staging with counted s_waitcnt vmcnt(4) + raw s_barrier.
// Tile j+2 issued right after the barrier of iter j -> ~2 compute iterations
// for loads to land. Verified R5: total 176 -> 164 us.
__global__ __launch_bounds__(256, 2) void attn_kernel(
    const __bf16* __restrict__ qk, const __bf16* __restrict__ vt,
    __bf16* __restrict__ out)
{
    constexpr int T = 2048;
    __shared__ __align__(16) char pool[49152];
    __bf16* Ks = (__bf16*)pool;             // [3][64 keys][64 d] chunk-swizzled
    __bf16* Vt = (__bf16*)(pool + 24576);   // [3][64 d][64 t]  chunk-swizzled
    float*  Om = (float*)pool;              // alias: [128][68] f32 (34816 B)
    float*  Lm = (float*)(pool + 34816);    // [128]

    const int tid  = threadIdx.x;
    const int wave = tid >> 6;
    const int lane = tid & 63;
    const int wq = wave & 1, wg = wave >> 1;
    const int l32 = lane & 31, hh = lane >> 5;

    const int fid  = blockIdx.x;            // 0..511
    const int xcd  = fid & 7;
    const int hsel = fid >> 8;
    const int w    = (fid >> 3) & 31;
    const int qt   = hsel ? (7 - (w >> 2)) : ((w >> 2) + 8);
    const int bh   = xcd * 4 + (w & 3);
    const int b = bh >> 4, h = bh & 15;
    const int jmax = 2 * qt + 1;

    const size_t rowbase = (size_t)b * T;
    const __bf16* Kbase = qk + 1024 + h * 64;            // row stride 2048
    const __bf16* Vbase = vt + (size_t)bh * 64 * 2048;   // [d][t]

    // staging: 4x load16 per thread per tile (2 K rows-chunks + 2 V)
    const int sr   = tid >> 3;              // 0..31
    const int schf = (tid & 7) ^ (sr & 7);  // (sr+32)&7 == sr&7

    // ---- Q fragments (B-operand), scale*log2(e) folded ----
    constexpr float QSCALE = 0.125f * 1.4426950408889634f;
    bf16_8 aq[2][4];   // [qtile][d-frag]
    #pragma unroll
    for (int qq = 0; qq < 2; ++qq)
        #pragma unroll
        for (int df = 0; df < 4; ++df) {
            const __bf16* qp = qk + (rowbase + qt*128 + wq*64 + qq*32 + l32)*2048
                               + h*64 + df*16 + hh*8;
            bf16_8 v = *(const bf16_8*)qp;
            #pragma unroll
            for (int u = 0; u < 8; ++u) v[u] = (__bf16)((float)v[u] * QSCALE);
            aq[qq][df] = v;
        }

    // ---- prologue: stage tiles 0 and 1 into bufs 0 and 1 ----
    #pragma unroll
    for (int t0 = 0; t0 < 2; ++t0)
        #pragma unroll
        for (int p = 0; p < 2; ++p) {
            load16_to_lds(Kbase + (rowbase + t0*64 + sr + 32*p)*2048 + schf*8,
                          Ks + t0*4096 + p*2048 + wave*512);
            load16_to_lds(Vbase + (size_t)(sr + 32*p)*2048 + t0*64 + schf*8,
                          Vt + t0*4096 + p*2048 + wave*512);
        }

    f32_16 O[2][2];   // [dtile][qtile]
    #pragma unroll
    for (int dt = 0; dt < 2; ++dt)
        #pragma unroll
        for (int qq = 0; qq < 2; ++qq)
            #pragma unroll
            for (int r = 0; r < 16; ++r) O[dt][qq][r] = 0.f;
    float l_i[2] = {0.f, 0.f};

    int cur = 0;       // buf index of tile j
    int sb  = 2;       // buf index of tile j+2 (stage target)
    for (int j = 0; j <= jmax; ++j) {
        // tile j staged? (its 4 loads are the oldest; tile j+1's 4 may fly)
        if (j < jmax) asm volatile("s_waitcnt vmcnt(4)" ::: "memory");
        else          asm volatile("s_waitcnt vmcnt(0)" ::: "memory");
        __builtin_amdgcn_s_barrier();   // all waves: tile j staged, buf[sb] reads done

        const int jn = j + 2;
        if (jn <= jmax) {
            #pragma unroll
            for (int p = 0; p < 2; ++p) {
                load16_to_lds(Kbase + (rowbase + jn*64 + sr + 32*p)*2048 + schf*8,
                              Ks + sb*4096 + p*2048 + wave*512);
                load16_to_lds(Vbase + (size_t)(sr + 32*p)*2048 + jn*64 + schf*8,
                              Vt + sb*4096 + p*2048 + wave*512);
            }
        }

        // ---- S^T[32k x 64q] = K Q^T : A=K-frag, B=Q-frag, d-chained x4 ----
        const int krow = wg*32 + l32;
        const int ksw  = krow & 7;
        f32_16 S[2];
        __builtin_amdgcn_s_setprio(1);
        bf16_8 kf[4];
        #pragma unroll
        for (int df = 0; df < 4; ++df)
            kf[df] = *(const bf16_8*)&Ks[cur*4096 + krow*64 + (((2*df + hh) ^ ksw) << 3)];
        #pragma unroll
        for (int qq = 0; qq < 2; ++qq) {
            f32_16 z;
            #pragma unroll
            for (int r = 0; r < 16; ++r) z[r] = 0.f;
            #pragma unroll
            for (int df = 0; df < 4; ++df)
                z = __builtin_amdgcn_mfma_f32_32x32x16_bf16(kf[df], aq[qq][df], z, 0, 0, 0);
            S[qq] = z;
        }
        __builtin_amdgcn_s_setprio(0);

        // ---- exp2 + causal mask; pack P^T into PV B-frags (VALU only) ----
        const bool diag = (j >= 2*qt);
        unsigned fr[2][8];   // [qtile][khalf*4 + dword]
        #pragma unroll
        for (int qq = 0; qq < 2; ++qq) {
            float pe[16];
            const int qg = qt*128 + wq*64 + qq*32 + l32;
            #pragma unroll
            for (int r = 0; r < 16; ++r) {
                float e = fast_exp2(S[qq][r]);
                if (diag) {
                    int key = j*64 + wg*32 + (r&3) + 8*(r>>2) + 4*hh;
                    if (key > qg) e = 0.f;
                }
                pe[r] = e;
                l_i[qq] += e;
            }
            unsigned A = pk2(pe[0],  pe[1]),  Bv = pk2(pe[2],  pe[3]),
                     C = pk2(pe[4],  pe[5]),  D  = pk2(pe[6],  pe[7]),
                     E = pk2(pe[8],  pe[9]),  F  = pk2(pe[10], pe[11]),
                     G = pk2(pe[12], pe[13]), H  = pk2(pe[14], pe[15]);
            pswap(A, C); pswap(Bv, D); pswap(E, G); pswap(F, H);
            fr[qq][0] = A; fr[qq][1] = Bv; fr[qq][2] = C; fr[qq][3] = D;
            fr[qq][4] = E; fr[qq][5] = F;  fr[qq][6] = G; fr[qq][7] = H;
        }

        // ---- O^T += V^T P^T : A=V-frag (b128), B=P-frag (regs) ----
        __builtin_amdgcn_s_setprio(1);
        #pragma unroll
        for (int kh = 0; kh < 2; ++kh) {
            #pragma unroll
            for (int dt = 0; dt < 2; ++dt) {
                const int d = dt*32 + l32;
                bf16_8 vf = *(const bf16_8*)&Vt[cur*4096 + d*64 +
                                (((wg*4 + kh*2 + hh) ^ (d & 7)) << 3)];
                #pragma unroll
                for (int qq = 0; qq < 2; ++qq) {
                    union { unsigned dw[4]; bf16_8 v; } u;
                    u.dw[0] = fr[qq][kh*4+0]; u.dw[1] = fr[qq][kh*4+1];
                    u.dw[2] = fr[qq][kh*4+2]; u.dw[3] = fr[qq][kh*4+3];
                    O[dt][qq] = __builtin_amdgcn_mfma_f32_32x32x16_bf16(
                        vf, u.v, O[dt][qq], 0, 0, 0);
                }
            }
        }
        __builtin_amdgcn_s_setprio(0);

        cur = (cur == 2) ? 0 : cur + 1;
        sb  = (sb  == 2) ? 0 : sb  + 1;
    }

    // ---- l: own 16 rows + partner half via xor-32 ----
    float lw[2];
    #pragma unroll
    for (int qq = 0; qq < 2; ++qq) {
        float v = l_i[qq];
        v += __shfl_xor(v, 32, 64);
        lw[qq] = v;
    }

    // ---- 2-way wg merge via LDS (Om aliases K/V pool) ----
    __syncthreads();   // all Ks/Vt reads done before Om aliases the pool
    if (wg == 1) {
        #pragma unroll
        for (int qq = 0; qq < 2; ++qq) {
            const int qrow = wq*64 + qq*32 + l32;
            #pragma unroll
            for (int dt = 0; dt < 2; ++dt)
                #pragma unroll
                for (int g = 0; g < 4; ++g) {
                    f32_4 t = { O[dt][qq][g*4+0], O[dt][qq][g*4+1],
                                O[dt][qq][g*4+2], O[dt][qq][g*4+3] };
                    *(f32_4*)&Om[qrow*68 + dt*32 + g*8 + hh*4] = t;
                }
            if (hh == 0) Lm[qrow] = lw[qq];
        }
    }
    __syncthreads();
    if (wg == 0) {
        #pragma unroll
        for (int qq = 0; qq < 2; ++qq) {
            const int qrow = wq*64 + qq*32 + l32;
            const float inv = 1.f / (lw[qq] + Lm[qrow]);
            const size_t obase = (rowbase + qt*128 + qrow) * 1024 + h*64;
            #pragma unroll
            for (int dt = 0; dt < 2; ++dt)
                #pragma unroll
                for (int g = 0; g < 4; ++g) {
                    f32_4 o2 = *(const f32_4*)&Om[qrow*68 + dt*32 + g*8 + hh*4];
                    bf16_4 ov;
                    #pragma unroll
                    for (int r = 0; r < 4; ++r)
                        ov[r] = (__bf16)((O[dt][qq][g*4+r] + o2[r]) * inv);
                    *(bf16_4*)(out + obase + dt*32 + g*8 + hh*4) = ov;
                }
        }
    }
}

// ---------------- launch ----------------
extern "C" void kernel_launch(void* const* d_in, const int* in_sizes, int n_in,
                              void* d_out, int out_size, void* d_ws, size_t ws_size,
                              hipStream_t stream)
{
    constexpr int Bc = 2, Tc = 2048, Dc = 1024;
    constexpr int M  = Bc * Tc;
    constexpr int N1 = 3 * Dc;

    const float* x     = (const float*)d_in[0];
    const float* Wqkv  = (const float*)d_in[1];
    const float* bqkv  = (const float*)d_in[2];
    const float* Wproj = (const float*)d_in[3];
    const float* bproj = (const float*)d_in[4];
    float* outp = (float*)d_out;

    __bf16* xb     = (__bf16*)d_ws;                        // 4096*1024
    __bf16* wqkvb  = xb     + (size_t)M * Dc;              // 3072*1024
    __bf16* wprojb = wqkvb  + (size_t)N1 * Dc;             // 1024*1024
    __bf16* qkb    = wprojb + (size_t)Dc * Dc;             // 4096*2048 (Q|K)
    __bf16* vtb    = qkb    + (size_t)M * 2048;            // 2*1024*2048 (V^T)
    __bf16* attnb  = vtb    + (size_t)Bc * 1024 * 2048;    // 4096*1024

    {
        int na4 = M * Dc / 4, nb4 = N1 * Dc / 4, nc4 = Dc * Dc / 4;
        int n4 = na4 + nb4 + nc4;
        cvt_all<<<(n4 + 255) / 256, 256, 0, stream>>>(x, Wqkv, Wproj, xb, na4, nb4, nc4);
    }

    gemm_bt<1, 128, 1, 0><<<dim3(N1 / 128, M / BM), 256, 0, stream>>>(
        xb, wqkvb, bqkv, qkb, nullptr, vtb, M, N1, Dc, 2048);

    attn_kernel<<<dim3(512), 256, 0, stream>>>(qkb, vtb, attnb);

    gemm_bt<0, 64, 0, 1><<<dim3(Dc / 64, M / BM), 256, 0, stream>>>(
        attnb, wprojb, bproj, nullptr, outp, nullptr, M, Dc, Dc, Dc);
}

// Round 8
// 160.597 us; speedup vs baseline: 1.0545x; 1.0140x over previous
//
#include <hip/hip_runtime.h>

// ---------------- types ----------------
typedef __bf16 bf16_8 __attribute__((ext_vector_type(8)));
typedef __bf16 bf16_4 __attribute__((ext_vector_type(4)));
typedef __bf16 bf16_2 __attribute__((ext_vector_type(2)));
typedef float  f32_4  __attribute__((ext_vector_type(4)));
typedef float  f32_16 __attribute__((ext_vector_type(16)));

typedef __attribute__((address_space(1))) const void* as1_cvp;
typedef __attribute__((address_space(3))) void*       as3_vp;

__device__ __forceinline__ void load16_to_lds(const void* g, void* l) {
    __builtin_amdgcn_global_load_lds((as1_cvp)g, (as3_vp)l, 16, 0, 0);
}

// hardware 2^x (v_exp_f32); scale log2(e) is folded into Q at load time
__device__ __forceinline__ float fast_exp2(float x) {
#if __has_builtin(__builtin_amdgcn_exp2f)
    return __builtin_amdgcn_exp2f(x);
#else
    return exp2f(x);
#endif
}

// pack two f32 -> one dword of 2 bf16 (compiler emits cvt+pack)
__device__ __forceinline__ unsigned pk2(float lo, float hi) {
    union { bf16_2 h; unsigned u; } t;
    t.h = bf16_2{(__bf16)lo, (__bf16)hi};
    return t.u;
}

// v_permlane32_swap_b32: a <- [a.lo | b.lo], b <- [a.hi | b.hi]
__device__ __forceinline__ void pswap(unsigned &a, unsigned &b) {
    asm("v_permlane32_swap_b32 %0, %1" : "+v"(a), "+v"(b));
}

// ---------------- fused fp32 -> bf16 convert (x | Wqkv | Wproj) ----------------
__global__ __launch_bounds__(256) void cvt_all(
    const float* __restrict__ a, const float* __restrict__ b,
    const float* __restrict__ c, __bf16* __restrict__ out,
    int na4, int nb4, int nc4)
{
    int i = blockIdx.x * 256 + threadIdx.x;
    if (i >= na4 + nb4 + nc4) return;
    float4 f;
    if (i < na4)            f = ((const float4*)a)[i];
    else if (i < na4 + nb4) f = ((const float4*)b)[i - na4];
    else                    f = ((const float4*)c)[i - na4 - nb4];
    bf16_4 v = { (__bf16)f.x, (__bf16)f.y, (__bf16)f.z, (__bf16)f.w };
    ((bf16_4*)out)[i] = v;
}

// ---------------- bf16 GEMM: C[M,N] = A[M,K] * B[N,K]^T + bias ----------------
// QKV==1: N=3072 logical; cols <2048 (Q|K) stored to Cb with row stride ldc=2048;
// cols >=2048 (V) stored TRANSPOSED to Vtb as [b][h*64+d][t] directly from
// accumulators (R5-verified direct stores).
// PIPE==1 (proj): triple-buffered staging + counted s_waitcnt vmcnt(6) +
// raw s_barrier (T4) -- verified R7.
#define BM 128

template<int OUT_BF16, int BN_, int QKV, int PIPE>
__global__ __launch_bounds__(256) void gemm_bt(
    const __bf16* __restrict__ A,   // [M,K]
    const __bf16* __restrict__ B,   // [N,K]
    const float*  __restrict__ bias,// [N] or nullptr
    __bf16* __restrict__ Cb, float* __restrict__ Cf,
    __bf16* __restrict__ Vtb,
    int M, int N, int K, int ldc)
{
    constexpr int NT   = BN_ / 32;
    constexpr int CSTR = BN_ + (OUT_BF16 ? 8 : 4);
    constexpr int BUFB = (128 * 64 + BN_ * 64) * 2;          // bytes per stage buf
    constexpr int SMEMSZ = PIPE ? (3 * BUFB) : 35840;
    __shared__ __align__(16) char smem[SMEMSZ];

    const int tid  = threadIdx.x;
    const int wave = tid >> 6;
    const int lane = tid & 63;
    const int wm = wave >> 1, wn = wave & 1;
    const int quad = lane >> 4, l16 = lane & 15;
    const int bm = blockIdx.y * BM, bn = blockIdx.x * BN_;

    const int r0 = tid >> 3;
    const int ch = tid & 7;
    const int cs = (ch ^ (r0 & 7)) * 8;

    f32_4 acc[4][NT];
    #pragma unroll
    for (int i = 0; i < 4; ++i)
        #pragma unroll
        for (int j = 0; j < NT; ++j)
            acc[i][j] = f32_4{0.f, 0.f, 0.f, 0.f};

    if constexpr (!PIPE) {
        __bf16* As = (__bf16*)smem;          // [128][64]
        __bf16* Bs = As + 128 * 64;          // [BN_][64]
        for (int k0 = 0; k0 < K; k0 += 64) {
            __syncthreads();
            #pragma unroll
            for (int p = 0; p < 4; ++p) {
                int row = p * 32 + r0;
                load16_to_lds(A + (size_t)(bm + row) * K + k0 + cs,
                              &As[(p * 32 + wave * 8) * 64]);
            }
            #pragma unroll
            for (int p = 0; p < BN_ / 32; ++p) {
                int row = p * 32 + r0;
                load16_to_lds(B + (size_t)(bn + row) * K + k0 + cs,
                              &Bs[(p * 32 + wave * 8) * 64]);
            }
            __syncthreads();

            #pragma unroll
            for (int h = 0; h < 2; ++h) {
                const int sl = ((quad + h * 4) ^ (l16 & 7)) * 8;
                bf16_8 af[4], bfr[NT];
                #pragma unroll
                for (int mt = 0; mt < 4; ++mt)
                    af[mt] = *(const bf16_8*)&As[(wm * 64 + mt * 16 + l16) * 64 + sl];
                #pragma unroll
                for (int nt = 0; nt < NT; ++nt)
                    bfr[nt] = *(const bf16_8*)&Bs[(wn * (BN_/2) + nt * 16 + l16) * 64 + sl];
                #pragma unroll
                for (int mt = 0; mt < 4; ++mt)
                    #pragma unroll
                    for (int nt = 0; nt < NT; ++nt)
                        acc[mt][nt] = __builtin_amdgcn_mfma_f32_16x16x32_bf16(
                            af[mt], bfr[nt], acc[mt][nt], 0, 0, 0);
            }
        }
    } else {
        // ---- T4: triple-buffered, counted vmcnt; 6 loads/thread/tile ----
        const int nit = K / 64;
        #pragma unroll
        for (int t = 0; t < 2; ++t) {
            __bf16* AsT = (__bf16*)(smem + t * BUFB);
            __bf16* BsT = AsT + 128 * 64;
            #pragma unroll
            for (int p = 0; p < 4; ++p)
                load16_to_lds(A + (size_t)(bm + p * 32 + r0) * K + t * 64 + cs,
                              &AsT[(p * 32 + wave * 8) * 64]);
            #pragma unroll
            for (int p = 0; p < BN_ / 32; ++p)
                load16_to_lds(B + (size_t)(bn + p * 32 + r0) * K + t * 64 + cs,
                              &BsT[(p * 32 + wave * 8) * 64]);
        }
        int cur = 0, sb = 2;
        for (int j = 0; j < nit; ++j) {
            if (j < nit - 1) asm volatile("s_waitcnt vmcnt(6)" ::: "memory");
            else             asm volatile("s_waitcnt vmcnt(0)" ::: "memory");
            __builtin_amdgcn_s_barrier();   // tile j staged; buf[sb] reads done

            if (j + 2 < nit) {
                const int k0 = (j + 2) * 64;
                __bf16* AsT = (__bf16*)(smem + sb * BUFB);
                __bf16* BsT = AsT + 128 * 64;
                #pragma unroll
                for (int p = 0; p < 4; ++p)
                    load16_to_lds(A + (size_t)(bm + p * 32 + r0) * K + k0 + cs,
                                  &AsT[(p * 32 + wave * 8) * 64]);
                #pragma unroll
                for (int p = 0; p < BN_ / 32; ++p)
                    load16_to_lds(B + (size_t)(bn + p * 32 + r0) * K + k0 + cs,
                                  &BsT[(p * 32 + wave * 8) * 64]);
            }

            __bf16* As = (__bf16*)(smem + cur * BUFB);
            __bf16* Bs = As + 128 * 64;
            #pragma unroll
            for (int h = 0; h < 2; ++h) {
                const int sl = ((quad + h * 4) ^ (l16 & 7)) * 8;
                bf16_8 af[4], bfr[NT];
                #pragma unroll
                for (int mt = 0; mt < 4; ++mt)
                    af[mt] = *(const bf16_8*)&As[(wm * 64 + mt * 16 + l16) * 64 + sl];
                #pragma unroll
                for (int nt = 0; nt < NT; ++nt)
                    bfr[nt] = *(const bf16_8*)&Bs[(wn * (BN_/2) + nt * 16 + l16) * 64 + sl];
                #pragma unroll
                for (int mt = 0; mt < 4; ++mt)
                    #pragma unroll
                    for (int nt = 0; nt < NT; ++nt)
                        acc[mt][nt] = __builtin_amdgcn_mfma_f32_16x16x32_bf16(
                            af[mt], bfr[nt], acc[mt][nt], 0, 0, 0);
            }
            cur = (cur == 2) ? 0 : cur + 1;
            sb  = (sb  == 2) ? 0 : sb  + 1;
        }
    }

    if (QKV && bn >= 2048) {
        // ---- V tile: store transposed directly (V^T[b][h*64+d][t]) ----
        const int b_ = bm >> 11;
        const int t0 = (bm & 2047) + wm * 64;
        #pragma unroll
        for (int nt = 0; nt < NT; ++nt) {
            int vrow = (bn - 2048) + wn * (BN_/2) + nt * 16 + l16;   // h*64+d
            float bv = bias ? bias[2048 + vrow] : 0.f;
            #pragma unroll
            for (int mt = 0; mt < 4; ++mt) {
                bf16_4 ov;
                #pragma unroll
                for (int r = 0; r < 4; ++r)
                    ov[r] = (__bf16)(acc[mt][nt][r] + bv);
                *(bf16_4*)(Vtb + ((size_t)b_ * 1024 + vrow) * 2048
                           + t0 + mt * 16 + quad * 4) = ov;
            }
        }
        return;
    }

    __syncthreads();

    if (OUT_BF16) {
        __bf16* Cs = (__bf16*)smem;
        #pragma unroll
        for (int mt = 0; mt < 4; ++mt)
            #pragma unroll
            for (int nt = 0; nt < NT; ++nt) {
                int col = wn * (BN_/2) + nt * 16 + l16;
                float bv = bias ? bias[bn + col] : 0.f;
                #pragma unroll
                for (int r = 0; r < 4; ++r)
                    Cs[(wm * 64 + mt * 16 + quad * 4 + r) * CSTR + col] =
                        (__bf16)(acc[mt][nt][r] + bv);
            }
        __syncthreads();
        const int rr = tid >> 4, cc = (tid & 15) * 8;
        #pragma unroll
        for (int p = 0; p < 8; ++p) {
            int row = p * 16 + rr;
            bf16_8 v = *(const bf16_8*)&Cs[row * CSTR + cc];
            *(bf16_8*)(Cb + (size_t)(bm + row) * ldc + bn + cc) = v;
        }
    } else {
        float* Cs = (float*)smem;
        #pragma unroll
        for (int mt = 0; mt < 4; ++mt)
            #pragma unroll
            for (int nt = 0; nt < NT; ++nt) {
                int col = wn * (BN_/2) + nt * 16 + l16;
                float bv = bias ? bias[bn + col] : 0.f;
                #pragma unroll
                for (int r = 0; r < 4; ++r)
                    Cs[(wm * 64 + mt * 16 + quad * 4 + r) * CSTR + col] =
                        acc[mt][nt][r] + bv;
            }
        __syncthreads();
        const int rr = tid >> 4, cc = (tid & 15) * 4;
        #pragma unroll
        for (int p = 0; p < 8; ++p) {
            int row = p * 16 + rr;
            float4 v = *(const float4*)&Cs[row * CSTR + cc];
            *(float4*)(Cf + (size_t)(bm + row) * ldc + bn + cc) = v;
        }
    }
}

// ---------------- causal flash attention v13: KVBLK=128 ----------------
// v11 compute, but 128-key tiles processed as two sequential 64-key halves
// per iteration: HALF the barrier/vmcnt rounds (qt+1 iters/block, uniform
// 17 per CU-pair vs 34-36). Register peak unchanged (S/fr reused per half).
// Double-buffered (2 x 32 KB LDS), drain vmcnt(0) at top: next tile issued
// right after the barrier -> window = one full double-length iteration
// (>1000 cy) >> L2-hit latency. Causal mask needed on only the last iter.
__global__ __launch_bounds__(256, 2) void attn_kernel(
    const __bf16* __restrict__ qk, const __bf16* __restrict__ vt,
    __bf16* __restrict__ out)
{
    constexpr int T = 2048;
    __shared__ __align__(16) char pool[65536];
    // per buf (32768 B = 16384 bf16): K [2 sub][64 k][64 d] then V [2 sub][64 d][64 t]
    __bf16* Ks = (__bf16*)pool;             // buf stride 16384 elems; V at +8192
    float*  Om = (float*)pool;              // alias: [128][68] f32 (34816 B)
    float*  Lm = (float*)(pool + 34816);    // [128]

    const int tid  = threadIdx.x;
    const int wave = tid >> 6;
    const int lane = tid & 63;
    const int wq = wave & 1, wg = wave >> 1;
    const int l32 = lane & 31, hh = lane >> 5;

    const int fid  = blockIdx.x;            // 0..511
    const int xcd  = fid & 7;
    const int hsel = fid >> 8;
    const int w    = (fid >> 3) & 31;
    const int qt   = hsel ? (7 - (w >> 2)) : ((w >> 2) + 8);
    const int bh   = xcd * 4 + (w & 3);
    const int b = bh >> 4, h = bh & 15;

    const size_t rowbase = (size_t)b * T;
    const __bf16* Kbase = qk + 1024 + h * 64;            // row stride 2048
    const __bf16* Vbase = vt + (size_t)bh * 64 * 2048;   // [d][t]

    // staging: 8x load16 per thread per 128-key tile (4 K + 4 V)
    const int sr   = tid >> 3;              // 0..31
    const int schf = (tid & 7) ^ (sr & 7);  // (sr+32)&7 == sr&7

    // ---- Q fragments (B-operand), scale*log2(e) folded ----
    constexpr float QSCALE = 0.125f * 1.4426950408889634f;
    bf16_8 aq[2][4];   // [qtile][d-frag]
    #pragma unroll
    for (int qq = 0; qq < 2; ++qq)
        #pragma unroll
        for (int df = 0; df < 4; ++df) {
            const __bf16* qp = qk + (rowbase + qt*128 + wq*64 + qq*32 + l32)*2048
                               + h*64 + df*16 + hh*8;
            bf16_8 v = *(const bf16_8*)qp;
            #pragma unroll
            for (int u = 0; u < 8; ++u) v[u] = (__bf16)((float)v[u] * QSCALE);
            aq[qq][df] = v;
        }

    // ---- prologue: stage tile 0 (128 keys) into buf 0 ----
    #pragma unroll
    for (int sub = 0; sub < 2; ++sub)
        #pragma unroll
        for (int p = 0; p < 2; ++p) {
            load16_to_lds(Kbase + (rowbase + sub*64 + sr + 32*p)*2048 + schf*8,
                          Ks + sub*4096 + p*2048 + wave*512);
            load16_to_lds(Vbase + (size_t)(sr + 32*p)*2048 + sub*64 + schf*8,
                          Ks + 8192 + sub*4096 + p*2048 + wave*512);
        }

    f32_16 O[2][2];   // [dtile][qtile]
    #pragma unroll
    for (int dt = 0; dt < 2; ++dt)
        #pragma unroll
        for (int qq = 0; qq < 2; ++qq)
            #pragma unroll
            for (int r = 0; r < 16; ++r) O[dt][qq][r] = 0.f;
    float l_i[2] = {0.f, 0.f};

    const int krow = wg*32 + l32;
    const int ksw  = krow & 7;

    for (int j = 0; j <= qt; ++j) {
        const int cur = j & 1, nxt = cur ^ 1;
        asm volatile("s_waitcnt vmcnt(0)" ::: "memory");   // tile j staged
        __builtin_amdgcn_s_barrier();                      // + buf[nxt] reads done

        if (j < qt) {
            const int jn = j + 1;
            #pragma unroll
            for (int sub = 0; sub < 2; ++sub)
                #pragma unroll
                for (int p = 0; p < 2; ++p) {
                    load16_to_lds(Kbase + (rowbase + jn*128 + sub*64 + sr + 32*p)*2048 + schf*8,
                                  Ks + nxt*16384 + sub*4096 + p*2048 + wave*512);
                    load16_to_lds(Vbase + (size_t)(sr + 32*p)*2048 + jn*128 + sub*64 + schf*8,
                                  Ks + nxt*16384 + 8192 + sub*4096 + p*2048 + wave*512);
                }
        }

        const bool diag = (j == qt);
        #pragma unroll
        for (int s2 = 0; s2 < 2; ++s2) {
            const __bf16* Kc = Ks + cur*16384 + s2*4096;
            const __bf16* Vc = Ks + cur*16384 + 8192 + s2*4096;

            // ---- S^T[32k x 64q] = K Q^T : A=K-frag, B=Q-frag, d-chained x4 ----
            f32_16 S[2];
            __builtin_amdgcn_s_setprio(1);
            bf16_8 kf[4];
            #pragma unroll
            for (int df = 0; df < 4; ++df)
                kf[df] = *(const bf16_8*)&Kc[krow*64 + (((2*df + hh) ^ ksw) << 3)];
            #pragma unroll
            for (int qq = 0; qq < 2; ++qq) {
                f32_16 z;
                #pragma unroll
                for (int r = 0; r < 16; ++r) z[r] = 0.f;
                #pragma unroll
                for (int df = 0; df < 4; ++df)
                    z = __builtin_amdgcn_mfma_f32_32x32x16_bf16(kf[df], aq[qq][df], z, 0, 0, 0);
                S[qq] = z;
            }
            __builtin_amdgcn_s_setprio(0);

            // ---- exp2 + causal mask; pack P^T into PV B-frags (VALU only) ----
            unsigned fr[2][8];   // [qtile][khalf*4 + dword]
            #pragma unroll
            for (int qq = 0; qq < 2; ++qq) {
                float pe[16];
                const int qg = qt*128 + wq*64 + qq*32 + l32;
                #pragma unroll
                for (int r = 0; r < 16; ++r) {
                    float e = fast_exp2(S[qq][r]);
                    if (diag) {
                        int key = j*128 + s2*64 + wg*32 + (r&3) + 8*(r>>2) + 4*hh;
                        if (key > qg) e = 0.f;
                    }
                    pe[r] = e;
                    l_i[qq] += e;
                }
                unsigned A = pk2(pe[0],  pe[1]),  Bv = pk2(pe[2],  pe[3]),
                         C = pk2(pe[4],  pe[5]),  D  = pk2(pe[6],  pe[7]),
                         E = pk2(pe[8],  pe[9]),  F  = pk2(pe[10], pe[11]),
                         G = pk2(pe[12], pe[13]), H  = pk2(pe[14], pe[15]);
                pswap(A, C); pswap(Bv, D); pswap(E, G); pswap(F, H);
                fr[qq][0] = A; fr[qq][1] = Bv; fr[qq][2] = C; fr[qq][3] = D;
                fr[qq][4] = E; fr[qq][5] = F;  fr[qq][6] = G; fr[qq][7] = H;
            }

            // ---- O^T += V^T P^T : A=V-frag (b128), B=P-frag (regs) ----
            __builtin_amdgcn_s_setprio(1);
            #pragma unroll
            for (int kh = 0; kh < 2; ++kh) {
                #pragma unroll
                for (int dt = 0; dt < 2; ++dt) {
                    const int d = dt*32 + l32;
                    bf16_8 vf = *(const bf16_8*)&Vc[d*64 +
                                    (((wg*4 + kh*2 + hh) ^ (d & 7)) << 3)];
                    #pragma unroll
                    for (int qq = 0; qq < 2; ++qq) {
                        union { unsigned dw[4]; bf16_8 v; } u;
                        u.dw[0] = fr[qq][kh*4+0]; u.dw[1] = fr[qq][kh*4+1];
                        u.dw[2] = fr[qq][kh*4+2]; u.dw[3] = fr[qq][kh*4+3];
                        O[dt][qq] = __builtin_amdgcn_mfma_f32_32x32x16_bf16(
                            vf, u.v, O[dt][qq], 0, 0, 0);
                    }
                }
            }
            __builtin_amdgcn_s_setprio(0);
        }
    }

    // ---- l: own 16 rows + partner half via xor-32 ----
    float lw[2];
    #pragma unroll
    for (int qq = 0; qq < 2; ++qq) {
        float v = l_i[qq];
        v += __shfl_xor(v, 32, 64);
        lw[qq] = v;
    }

    // ---- 2-way wg merge via LDS (Om aliases K/V pool) ----
    __syncthreads();   // all Ks/V reads done before Om aliases the pool
    if (wg == 1) {
        #pragma unroll
        for (int qq = 0; qq < 2; ++qq) {
            const int qrow = wq*64 + qq*32 + l32;
            #pragma unroll
            for (int dt = 0; dt < 2; ++dt)
                #pragma unroll
                for (int g = 0; g < 4; ++g) {
                    f32_4 t = { O[dt][qq][g*4+0], O[dt][qq][g*4+1],
                                O[dt][qq][g*4+2], O[dt][qq][g*4+3] };
                    *(f32_4*)&Om[qrow*68 + dt*32 + g*8 + hh*4] = t;
                }
            if (hh == 0) Lm[qrow] = lw[qq];
        }
    }
    __syncthreads();
    if (wg == 0) {
        #pragma unroll
        for (int qq = 0; qq < 2; ++qq) {
            const int qrow = wq*64 + qq*32 + l32;
            const float inv = 1.f / (lw[qq] + Lm[qrow]);
            const size_t obase = (rowbase + qt*128 + qrow) * 1024 + h*64;
            #pragma unroll
            for (int dt = 0; dt < 2; ++dt)
                #pragma unroll
                for (int g = 0; g < 4; ++g) {
                    f32_4 o2 = *(const f32_4*)&Om[qrow*68 + dt*32 + g*8 + hh*4];
                    bf16_4 ov;
                    #pragma unroll
                    for (int r = 0; r < 4; ++r)
                        ov[r] = (__bf16)((O[dt][qq][g*4+r] + o2[r]) * inv);
                    *(bf16_4*)(out + obase + dt*32 + g*8 + hh*4) = ov;
                }
        }
    }
}

// ---------------- launch ----------------
extern "C" void kernel_launch(void* const* d_in, const int* in_sizes, int n_in,
                              void* d_out, int out_size, void* d_ws, size_t ws_size,
                              hipStream_t stream)
{
    constexpr int Bc = 2, Tc = 2048, Dc = 1024;
    constexpr int M  = Bc * Tc;
    constexpr int N1 = 3 * Dc;

    const float* x     = (const float*)d_in[0];
    const float* Wqkv  = (const float*)d_in[1];
    const float* bqkv  = (const float*)d_in[2];
    const float* Wproj = (const float*)d_in[3];
    const float* bproj = (const float*)d_in[4];
    float* outp = (float*)d_out;

    __bf16* xb     = (__bf16*)d_ws;                        // 4096*1024
    __bf16* wqkvb  = xb     + (size_t)M * Dc;              // 3072*1024
    __bf16* wprojb = wqkvb  + (size_t)N1 * Dc;             // 1024*1024
    __bf16* qkb    = wprojb + (size_t)Dc * Dc;             // 4096*2048 (Q|K)
    __bf16* vtb    = qkb    + (size_t)M * 2048;            // 2*1024*2048 (V^T)
    __bf16* attnb  = vtb    + (size_t)Bc * 1024 * 2048;    // 4096*1024

    {
        int na4 = M * Dc / 4, nb4 = N1 * Dc / 4, nc4 = Dc * Dc / 4;
        int n4 = na4 + nb4 + nc4;
        cvt_all<<<(n4 + 255) / 256, 256, 0, stream>>>(x, Wqkv, Wproj, xb, na4, nb4, nc4);
    }

    gemm_bt<1, 128, 1, 0><<<dim3(N1 / 128, M / BM), 256, 0, stream>>>(
        xb, wqkvb, bqkv, qkb, nullptr, vtb, M, N1, Dc, 2048);

    attn_kernel<<<dim3(512), 256, 0, stream>>>(qkb, vtb, attnb);

    gemm_bt<0, 64, 0, 1><<<dim3(Dc / 64, M / BM), 256, 0, stream>>>(
        attnb, wprojb, bproj, nullptr, outp, nullptr, M, Dc, Dc, Dc);
}